// Round 11
// baseline (997.777 us; speedup 1.0000x reference)
//
#include <hip/hip_runtime.h>

#define B 8
#define N 8192
#define S 1024
#define NS 32
#define THREADS 256
#define NCONS_BLK 248
#define NCONS_WAVE (NCONS_BLK * 4)
constexpr float BN_EPS = 1e-5f;

typedef float v2f __attribute__((ext_vector_type(2)));

struct KParams {
  const float* xyz;
  const float *w1, *b1, *g1, *be1, *m1, *v1;
  const float *w2, *b2, *g2, *be2, *m2, *v2;
  const float *w3, *b3, *g3, *be3, *m3, *v3;
  float* new_xyz;   // d_out (B,S,3)
  float* out_feat;  // d_out + B*S*3 (B,128,S)
  float* ctrs;      // d_ws+2048: (B, S*3) published centers
  unsigned* prog;   // d_ws: per-batch progress counter, 64-int stride
};

// DPP-based full-wave (64-lane) f32 max; result valid in lane 63.
__device__ __forceinline__ float wave_max_to_lane63(float x) {
  int v = __float_as_int(x);
#define DPP_MAX(ctrl)                                                     \
  v = __float_as_int(fmaxf(__int_as_float(v),                             \
      __int_as_float(__builtin_amdgcn_update_dpp(v, v, (ctrl), 0xf, 0xf, \
                                                 false))))
  DPP_MAX(0x111);
  DPP_MAX(0x112);
  DPP_MAX(0x114);
  DPP_MAX(0x118);
  DPP_MAX(0x142);
  DPP_MAX(0x143);
#undef DPP_MAX
  return __int_as_float(v);
}

// ---------------------------------------------------------------------------
// Producer: FPS, 4 waves (1/SIMD), 32 pts/thread. R11: the per-round
// s_barrier is REPLACED by seq-tagged LDS key exchange (release-store own
// slot, acquire-poll the other 3 in one overlapped load group). Rationale:
// per-round cost was ~1950 cy invariant across wave count/spill/issue changes
// (R4/R7/R9/R10) -> the fixed term is the barrier wake + the mandatory
// s_waitcnt vmcnt(0) drain before s_barrier (which stalls everyone on
// wave0's 24 publish stores every 8th round). No barrier -> no drain.
// Key layout: [63:32]=dist f32 bits, [31:19]... actually [25:13]=8191-idx,
// [12:0]=round tag. Same-round keys share the tag, so ordering is still
// (dist, then smaller index). Parity double-buffer gives ~2 rounds of
// overwrite margin for the exchange slots.
// Exact contract-off fp32 distance math -> argmax matches NumPy bit-for-bit.
// ---------------------------------------------------------------------------
__device__ __forceinline__ void producer(const KParams& P, char* smem, int b,
                                         int t, int lane, int w) {
#pragma clang fp contract(off)
  float4* s_xyz4 = (float4*)smem;                       // 128 KB
  float* s_ctr = (float*)(smem + 131072);               // 12 KB
  unsigned long long* s_red =
      (unsigned long long*)(smem + 131072 + 12288);     // 2 x 4 slots
  const float* base = P.xyz + (size_t)b * N * 3;
  v2f X[16], Y[16], Z[16], D[16];
  const int p0 = t * 32;
  {
    // 32 pts * 3 floats = 24 float4 loads, 16B-aligned (t*384 bytes);
    // mirrored float4-strided into LDS for 1-instr winner-coord broadcast.
    const float4* src = (const float4*)(base + (size_t)p0 * 3);
    float buf[96];
#pragma unroll
    for (int i = 0; i < 24; ++i) {
      float4 v = src[i];
      buf[4 * i + 0] = v.x; buf[4 * i + 1] = v.y;
      buf[4 * i + 2] = v.z; buf[4 * i + 3] = v.w;
    }
#pragma unroll
    for (int k = 0; k < 32; ++k)
      s_xyz4[p0 + k] =
          make_float4(buf[3 * k], buf[3 * k + 1], buf[3 * k + 2], 0.f);
#pragma unroll
    for (int i = 0; i < 16; ++i) {
      X[i] = (v2f){buf[6 * i + 0], buf[6 * i + 3]};
      Y[i] = (v2f){buf[6 * i + 1], buf[6 * i + 4]};
      Z[i] = (v2f){buf[6 * i + 2], buf[6 * i + 5]};
      D[i] = (v2f){3.4e38f, 3.4e38f};  // ref init +inf; min(inf,d)=d, d<=3
    }
  }
  __syncthreads();  // mirror complete before round-1 winner-coord reads
  float lx = base[0], ly = base[1], lz = base[2];  // start index 0
  if (t == 0) { s_ctr[0] = lx; s_ctr[1] = ly; s_ctr[2] = lz; }
  const int j1 = (w + 1) & 3, j2 = (w + 2) & 3, j3 = (w + 3) & 3;
  for (int r = 1; r < S; ++r) {
    v2f lx2 = lx, ly2 = ly, lz2 = lz;
    // exact: d = ((dx*dx)+(dy*dy))+(dz*dz), contraction off; pk ops round
    // identically to scalar per lane-half.
#pragma unroll
    for (int i = 0; i < 16; ++i) {
      v2f dx = X[i] - lx2, dy = Y[i] - ly2, dz = Z[i] - lz2;
      v2f d = (dx * dx + dy * dy) + dz * dz;
      D[i] = __builtin_elementwise_min(D[i], d);
    }
    // local max tree over 32 halves; prefer-left walk-down == first index
    float n1[16], n2[8], n3[4], n4[2];
#pragma unroll
    for (int i = 0; i < 16; ++i) n1[i] = fmaxf(D[i].x, D[i].y);
#pragma unroll
    for (int i = 0; i < 8; ++i) n2[i] = fmaxf(n1[2 * i], n1[2 * i + 1]);
#pragma unroll
    for (int i = 0; i < 4; ++i) n3[i] = fmaxf(n2[2 * i], n2[2 * i + 1]);
    n4[0] = fmaxf(n3[0], n3[1]);
    n4[1] = fmaxf(n3[2], n3[3]);
    float m = fmaxf(n4[0], n4[1]);
    int c4 = (n4[0] < m) ? 1 : 0;
    float n3s = c4 ? n3[2] : n3[0];
    int c3 = (n3s < m) ? 1 : 0;
    float n2a = c4 ? n2[4] : n2[0];
    float n2b = c4 ? n2[6] : n2[2];
    float n2s = c3 ? n2b : n2a;
    int c2 = (n2s < m) ? 1 : 0;
    float n1a = c4 ? n1[8] : n1[0];
    float n1b = c4 ? n1[10] : n1[2];
    float n1c = c4 ? n1[12] : n1[4];
    float n1d = c4 ? n1[14] : n1[6];
    float n1e = c3 ? n1c : n1a;
    float n1f = c3 ? n1d : n1b;
    float n1s = c2 ? n1f : n1e;
    int c1 = (n1s < m) ? 1 : 0;
    float e0 = c4 ? D[8].x : D[0].x;
    float e1 = c4 ? D[9].x : D[1].x;
    float e2 = c4 ? D[10].x : D[2].x;
    float e3 = c4 ? D[11].x : D[3].x;
    float e4 = c4 ? D[12].x : D[4].x;
    float e5 = c4 ? D[13].x : D[5].x;
    float e6 = c4 ? D[14].x : D[6].x;
    float e7 = c4 ? D[15].x : D[7].x;
    float f0 = c3 ? e4 : e0;
    float f1 = c3 ? e5 : e1;
    float f2 = c3 ? e6 : e2;
    float f3 = c3 ? e7 : e3;
    float g0 = c2 ? f2 : f0;
    float g1 = c2 ? f3 : f1;
    float dxs = c1 ? g1 : g0;
    int c0 = (dxs < m) ? 1 : 0;
    int li = 16 * c4 + 8 * c3 + 4 * c2 + 2 * c1 + c0;
    // wave max via DPP; index recovery via ballot (lane order == index order)
    float wm = wave_max_to_lane63(m);
    float wavemax =
        __int_as_float(__builtin_amdgcn_readlane(__float_as_int(wm), 63));
    unsigned long long bal = __ballot(m == wavemax);
    int firstlane = (int)__builtin_ctzll(bal);
    int widx = __builtin_amdgcn_readlane(p0 + li, firstlane);
    const unsigned tag = (unsigned)r & 0x1fffu;
    unsigned long long key =
        ((unsigned long long)__float_as_uint(wavemax) << 32) |
        ((unsigned)(8191 - widx) << 13) | tag;
    unsigned long long* sr = s_red + (r & 1) * 4;
    if (lane == 0)
      __hip_atomic_store(&sr[w], key, __ATOMIC_RELEASE,
                         __HIP_MEMORY_SCOPE_WORKGROUP);
    // acquire-poll the other 3 slots until all carry this round's tag
    unsigned long long ka, kb, kc;
    do {
      ka = __hip_atomic_load(&sr[j1], __ATOMIC_ACQUIRE,
                             __HIP_MEMORY_SCOPE_WORKGROUP);
      kb = __hip_atomic_load(&sr[j2], __ATOMIC_ACQUIRE,
                             __HIP_MEMORY_SCOPE_WORKGROUP);
      kc = __hip_atomic_load(&sr[j3], __ATOMIC_ACQUIRE,
                             __HIP_MEMORY_SCOPE_WORKGROUP);
    } while ((((unsigned)ka ^ tag) & 0x1fffu) |
             (((unsigned)kb ^ tag) & 0x1fffu) |
             (((unsigned)kc ^ tag) & 0x1fffu));
    unsigned long long kmax = key > ka ? key : ka;
    unsigned long long kcd = kb > kc ? kb : kc;
    kmax = kmax > kcd ? kmax : kcd;
    const int bi = 8191 - (int)(((unsigned)kmax >> 13) & 0x1fffu);
    float4 cc = s_xyz4[bi];  // ONE ds_read_b128, broadcast
    lx = cc.x; ly = cc.y; lz = cc.z;
    if (t == 0) {
      s_ctr[r * 3 + 0] = lx; s_ctr[r * 3 + 1] = ly; s_ctr[r * 3 + 2] = lz;
    }
    // Lagged publish (wave 0): release prog for chunk k-1 (those stores have
    // had 8 rounds to drain), then relaxed-store chunk k's coords. With no
    // barrier in the loop there is no forced vmcnt(0) drain anywhere.
    if (w == 0 && (r & 7) == 7) {
      int k8 = r >> 3;
      if (lane == 0 && k8 >= 1)
        __hip_atomic_store(&P.prog[b * 64], (unsigned)(k8 * 8),
                           __ATOMIC_RELEASE, __HIP_MEMORY_SCOPE_AGENT);
      int cbase = (r - 7) * 3;
      if (lane < 24)
        __hip_atomic_store(P.ctrs + (size_t)b * (S * 3) + cbase + lane,
                           s_ctr[cbase + lane], __ATOMIC_RELAXED,
                           __HIP_MEMORY_SCOPE_AGENT);
    }
  }
  __syncthreads();  // s_ctr complete before cooperative writeout
  if (w == 0 && lane == 0)  // final release covers the last 2 chunks
    __hip_atomic_store(&P.prog[b * 64], (unsigned)S, __ATOMIC_RELEASE,
                       __HIP_MEMORY_SCOPE_AGENT);
  float* o = P.new_xyz + (size_t)b * S * 3;
  for (int i = t; i < (S * 3) / 4; i += THREADS)
    ((float4*)o)[i] = ((const float4*)s_ctr)[i];
}

// ---------------------------------------------------------------------------
// Consumer: one wave per center (4 waves/block). Spin (s_sleep backoff) until
// the producer publishes center (b,s); ball query fused with coord gather;
// 3-layer BN-folded MLP + max. No block barriers (same-wave LDS RAW only).
// ---------------------------------------------------------------------------
__device__ __forceinline__ void consumer(const KParams& P, char* smem, int cid,
                                         int t, int lane, int w) {
#pragma clang fp contract(off)
  constexpr float R2 = (float)(0.2 * 0.2);
  float* h = (float*)smem + w * (NS * 64);              // 8 KB per wave
  float* cs = (float*)smem + 4 * NS * 64 + w * (NS * 4);
  const unsigned gw = cid * 4 + w;  // global consumer wave id, 0..991
  // BN-folded weights, loaded once per wave (registers)
  float sv1 = P.g1[lane] / sqrtf(P.v1[lane] + BN_EPS);
  float bb1 = (P.b1[lane] - P.m1[lane]) * sv1 + P.be1[lane];
  float w1x = P.w1[lane * 3 + 0] * sv1, w1y = P.w1[lane * 3 + 1] * sv1,
        w1z = P.w1[lane * 3 + 2] * sv1;
  float sv2 = P.g2[lane] / sqrtf(P.v2[lane] + BN_EPS);
  float bb2 = (P.b2[lane] - P.m2[lane]) * sv2 + P.be2[lane];
  float W2[64];
#pragma unroll
  for (int k = 0; k < 64; k += 4) {
    float4 q = *(const float4*)(P.w2 + lane * 64 + k);
    W2[k + 0] = q.x * sv2; W2[k + 1] = q.y * sv2;
    W2[k + 2] = q.z * sv2; W2[k + 3] = q.w * sv2;
  }
  float sva = P.g3[lane] / sqrtf(P.v3[lane] + BN_EPS);
  float bba = (P.b3[lane] - P.m3[lane]) * sva + P.be3[lane];
  float svb = P.g3[lane + 64] / sqrtf(P.v3[lane + 64] + BN_EPS);
  float bbb = (P.b3[lane + 64] - P.m3[lane + 64]) * svb + P.be3[lane + 64];
  float Wa[64], Wb[64];
#pragma unroll
  for (int k = 0; k < 64; k += 4) {
    float4 qa = *(const float4*)(P.w3 + lane * 64 + k);
    Wa[k + 0] = qa.x * sva; Wa[k + 1] = qa.y * sva;
    Wa[k + 2] = qa.z * sva; Wa[k + 3] = qa.w * sva;
    float4 qb = *(const float4*)(P.w3 + (lane + 64) * 64 + k);
    Wb[k + 0] = qb.x * svb; Wb[k + 1] = qb.y * svb;
    Wb[k + 2] = qb.z * svb; Wb[k + 3] = qb.w * svb;
  }
  for (unsigned c = gw; c < B * S; c += NCONS_WAVE) {
    const int b = c & 7;
    const int s = c >> 3;
    while (__hip_atomic_load(&P.prog[b * 64], __ATOMIC_RELAXED,
                             __HIP_MEMORY_SCOPE_AGENT) <= (unsigned)s)
      __builtin_amdgcn_s_sleep(8);
    (void)__hip_atomic_load(&P.prog[b * 64], __ATOMIC_ACQUIRE,
                            __HIP_MEMORY_SCOPE_AGENT);
    const float* cg = P.ctrs + (size_t)b * (S * 3) + s * 3;
    float cx = __hip_atomic_load(cg + 0, __ATOMIC_RELAXED,
                                 __HIP_MEMORY_SCOPE_AGENT);
    float cy = __hip_atomic_load(cg + 1, __ATOMIC_RELAXED,
                                 __HIP_MEMORY_SCOPE_AGENT);
    float cz = __hip_atomic_load(cg + 2, __ATOMIC_RELAXED,
                                 __HIP_MEMORY_SCOPE_AGENT);
    const float* base = P.xyz + (size_t)b * N * 3;
    // ball query fused with coord gather: finder lane scatters coords to cs
    int cnt = 0;
    for (int c0 = 0; c0 < N && cnt < NS; c0 += 64) {
      int p = c0 + lane;
      float x = base[p * 3], y = base[p * 3 + 1], z = base[p * 3 + 2];
      float dx = x - cx, dy = y - cy, dz = z - cz;
      float d = (dx * dx + dy * dy) + dz * dz;
      bool v = d < R2;  // strict <, exact fp32: matches reference
      unsigned long long mk = __ballot(v);
      int rank = cnt + __popcll(mk & ((1ull << lane) - 1ull));
      if (v && rank < NS) {
        cs[rank * 4 + 0] = x; cs[rank * 4 + 1] = y; cs[rank * 4 + 2] = z;
      }
      cnt += (int)__popcll(mk);
    }
    if (cnt < NS) {  // pad -> point 0 coords (pytorch3d clamp semantics)
      float x0 = base[0], y0 = base[1], z0 = base[2];
      for (int j = cnt + lane; j < NS; j += 64) {
        cs[j * 4 + 0] = x0; cs[j * 4 + 1] = y0; cs[j * 4 + 2] = z0;
      }
    }
    // layer 1: 3 -> 64
    for (int n = 0; n < NS; ++n) {
      float a = fmaf(w1x, cs[n * 4 + 0],
                     fmaf(w1y, cs[n * 4 + 1], fmaf(w1z, cs[n * 4 + 2], bb1)));
      h[n * 64 + lane] = fmaxf(a, 0.f);
    }
    // layer 2: 64 -> 64 (in-place row overwrite, wave-lockstep safe)
    for (int n = 0; n < NS; ++n) {
      float acc = bb2;
#pragma unroll
      for (int k = 0; k < 64; k += 4) {
        float4 q = *(const float4*)(h + n * 64 + k);
        acc = fmaf(W2[k + 0], q.x, acc);
        acc = fmaf(W2[k + 1], q.y, acc);
        acc = fmaf(W2[k + 2], q.z, acc);
        acc = fmaf(W2[k + 3], q.w, acc);
      }
      h[n * 64 + lane] = fmaxf(acc, 0.f);
    }
    // layer 3: 64 -> 128, both halves per pass, fused max over samples
    float mxa = 0.f, mxb = 0.f;
    for (int n = 0; n < NS; ++n) {
      float acca = bba, accb = bbb;
#pragma unroll
      for (int k = 0; k < 64; k += 4) {
        float4 q = *(const float4*)(h + n * 64 + k);
        acca = fmaf(Wa[k + 0], q.x, acca);
        acca = fmaf(Wa[k + 1], q.y, acca);
        acca = fmaf(Wa[k + 2], q.z, acca);
        acca = fmaf(Wa[k + 3], q.w, acca);
        accb = fmaf(Wb[k + 0], q.x, accb);
        accb = fmaf(Wb[k + 1], q.y, accb);
        accb = fmaf(Wb[k + 2], q.z, accb);
        accb = fmaf(Wb[k + 3], q.w, accb);
      }
      mxa = fmaxf(mxa, acca);
      mxb = fmaxf(mxb, accb);
    }
    P.out_feat[((size_t)b * 128 + lane) * S + s] = mxa;
    P.out_feat[((size_t)b * 128 + 64 + lane) * S + s] = mxb;
  }
}

// ---------------------------------------------------------------------------
__global__ void __attribute__((amdgpu_flat_work_group_size(THREADS, THREADS),
                               amdgpu_waves_per_eu(1, 1)))
k_fused(KParams P) {
  extern __shared__ char smem[];
  const int t = threadIdx.x;
  const int lane = t & 63;
  const int w = t >> 6;
  if (blockIdx.x < B)
    producer(P, smem, blockIdx.x, t, lane, w);
  else
    consumer(P, smem, blockIdx.x - B, t, lane, w);
}

// ---------------------------------------------------------------------------
extern "C" void kernel_launch(void* const* d_in, const int* in_sizes, int n_in,
                              void* d_out, int out_size, void* d_ws,
                              size_t ws_size, hipStream_t stream) {
  KParams P;
  P.xyz = (const float*)d_in[0];
  P.w1 = (const float*)d_in[1];  P.b1 = (const float*)d_in[2];
  P.g1 = (const float*)d_in[3];  P.be1 = (const float*)d_in[4];
  P.m1 = (const float*)d_in[5];  P.v1 = (const float*)d_in[6];
  P.w2 = (const float*)d_in[7];  P.b2 = (const float*)d_in[8];
  P.g2 = (const float*)d_in[9];  P.be2 = (const float*)d_in[10];
  P.m2 = (const float*)d_in[11]; P.v2 = (const float*)d_in[12];
  P.w3 = (const float*)d_in[13]; P.b3 = (const float*)d_in[14];
  P.g3 = (const float*)d_in[15]; P.be3 = (const float*)d_in[16];
  P.m3 = (const float*)d_in[17]; P.v3 = (const float*)d_in[18];
  float* out = (float*)d_out;
  P.new_xyz = out;
  P.out_feat = out + (size_t)B * S * 3;
  P.prog = (unsigned*)d_ws;                       // 8 x 64 u32 = 2 KB
  P.ctrs = (float*)((char*)d_ws + 2048);          // 96 KB

  // d_ws is re-poisoned to 0xAA before every timed launch: zero the progress
  // counters (async, graph-capturable) or consumers would see garbage.
  hipMemsetAsync(d_ws, 0, 2048, stream);

  // Plain launch (no cooperative overhead): 256 blocks x 140 KB LDS -> at
  // most 1 block/CU, and correctness does not require co-residency (late
  // consumer blocks find prog already advanced and just process).
  dim3 grid(B + NCONS_BLK), blk(THREADS);
  size_t shmem = 131072 + 12288 + 256;  // producer overlay is the max
  k_fused<<<grid, blk, shmem, stream>>>(P);
}

// Round 12
// 985.085 us; speedup vs baseline: 1.0129x; 1.0129x over previous
//
#include <hip/hip_runtime.h>

#define B 8
#define N 8192
#define S 1024
#define NS 32
#define THREADS 512
#define NCONS_BLK 248
#define NCONS_WAVE (NCONS_BLK * 8)
constexpr float BN_EPS = 1e-5f;

typedef float v2f __attribute__((ext_vector_type(2)));

struct KParams {
  const float* xyz;
  const float *w1, *b1, *g1, *be1, *m1, *v1;
  const float *w2, *b2, *g2, *be2, *m2, *v2;
  const float *w3, *b3, *g3, *be3, *m3, *v3;
  float* new_xyz;   // d_out (B,S,3)
  float* out_feat;  // d_out + B*S*3 (B,128,S)
  float* ctrs;      // d_ws+2048: (B, S*3) published centers
  unsigned* prog;   // d_ws: per-batch progress counter, 64-int stride
};

// DPP-based full-wave (64-lane) f32 max; result valid in lane 63.
__device__ __forceinline__ float wave_max_to_lane63(float x) {
  int v = __float_as_int(x);
#define DPP_MAX(ctrl)                                                     \
  v = __float_as_int(fmaxf(__int_as_float(v),                             \
      __int_as_float(__builtin_amdgcn_update_dpp(v, v, (ctrl), 0xf, 0xf, \
                                                 false))))
  DPP_MAX(0x111);
  DPP_MAX(0x112);
  DPP_MAX(0x114);
  DPP_MAX(0x118);
  DPP_MAX(0x142);
  DPP_MAX(0x143);
#undef DPP_MAX
  return __int_as_float(v);
}

// ---------------------------------------------------------------------------
// Producer: R7's measured-best FPS core (825 us): 8 waves (2/SIMD), 16
// pts/thread register-resident, ONE s_barrier per round (R11 proved the
// spin-exchange alternative is ~100 us WORSE), parallel 8-key LDS reduce,
// float4 LDS mirror for 1-instr winner-coord broadcast. Publish: lagged
// release every 16 rounds (release covers chunk k-1 whose stores drained
// ~16 rounds ago; fresh stores relaxed -> no fresh-store wait anywhere).
// Exact contract-off fp32 distance math -> argmax matches NumPy bit-for-bit;
// ties -> smallest index (prefer-left walk-down + (8191-idx) key low word).
// ---------------------------------------------------------------------------
__device__ __forceinline__ void producer(const KParams& P, char* smem, int b,
                                         int t, int lane, int w) {
#pragma clang fp contract(off)
  float4* s_xyz4 = (float4*)smem;                       // 128 KB
  float* s_ctr = (float*)(smem + 131072);               // 12 KB
  unsigned long long(*s_red)[8] =
      (unsigned long long(*)[8])(smem + 131072 + 12288);
  const float* base = P.xyz + (size_t)b * N * 3;
  v2f X[8], Y[8], Z[8], D[8];
  const int p0 = t * 16;
  {
    // 16 pts * 3 floats = 12 float4 loads, 16B-aligned (t*192 bytes);
    // mirrored float4-strided into LDS for winner-coord broadcast.
    const float4* src = (const float4*)(base + (size_t)p0 * 3);
    float buf[48];
#pragma unroll
    for (int i = 0; i < 12; ++i) {
      float4 v = src[i];
      buf[4 * i + 0] = v.x; buf[4 * i + 1] = v.y;
      buf[4 * i + 2] = v.z; buf[4 * i + 3] = v.w;
    }
#pragma unroll
    for (int k = 0; k < 16; ++k)
      s_xyz4[p0 + k] =
          make_float4(buf[3 * k], buf[3 * k + 1], buf[3 * k + 2], 0.f);
#pragma unroll
    for (int i = 0; i < 8; ++i) {
      X[i] = (v2f){buf[6 * i + 0], buf[6 * i + 3]};
      Y[i] = (v2f){buf[6 * i + 1], buf[6 * i + 4]};
      Z[i] = (v2f){buf[6 * i + 2], buf[6 * i + 5]};
      D[i] = (v2f){3.4e38f, 3.4e38f};  // ref init +inf; min(inf,d)=d, d<=3
    }
  }
  __syncthreads();  // mirror complete (round-1 coord read safety)
  float lx = base[0], ly = base[1], lz = base[2];  // start index 0
  if (t == 0) { s_ctr[0] = lx; s_ctr[1] = ly; s_ctr[2] = lz; }
  for (int r = 1; r < S; ++r) {
    v2f lx2 = lx, ly2 = ly, lz2 = lz;
    // exact: d = ((dx*dx)+(dy*dy))+(dz*dz), contraction off; pk ops round
    // identically to scalar per lane-half.
#pragma unroll
    for (int i = 0; i < 8; ++i) {
      v2f dx = X[i] - lx2, dy = Y[i] - ly2, dz = Z[i] - lz2;
      v2f d = (dx * dx + dy * dy) + dz * dz;
      D[i] = __builtin_elementwise_min(D[i], d);
    }
    // local max tree over 16 halves; prefer-left walk-down == first index
    float n1[8], n2[4], n3[2];
#pragma unroll
    for (int i = 0; i < 8; ++i) n1[i] = fmaxf(D[i].x, D[i].y);
#pragma unroll
    for (int i = 0; i < 4; ++i) n2[i] = fmaxf(n1[2 * i], n1[2 * i + 1]);
    n3[0] = fmaxf(n2[0], n2[1]);
    n3[1] = fmaxf(n2[2], n2[3]);
    float m = fmaxf(n3[0], n3[1]);
    int c3 = (n3[0] < m) ? 1 : 0;
    float n2s = c3 ? n2[2] : n2[0];
    int c2 = (n2s < m) ? 1 : 0;
    float n1a = c3 ? n1[4] : n1[0];
    float n1b = c3 ? n1[6] : n1[2];
    float n1s = c2 ? n1b : n1a;
    int c1 = (n1s < m) ? 1 : 0;
    float dx0 = c3 ? D[4].x : D[0].x;
    float dx1 = c3 ? D[5].x : D[1].x;
    float dx2 = c3 ? D[6].x : D[2].x;
    float dx3 = c3 ? D[7].x : D[3].x;
    float dxa = c2 ? dx2 : dx0;
    float dxb = c2 ? dx3 : dx1;
    float dxs = c1 ? dxb : dxa;
    int c0 = (dxs < m) ? 1 : 0;
    int li = 8 * c3 + 4 * c2 + 2 * c1 + c0;
    // wave max via DPP; index recovery via ballot (lane order == index order)
    float wm = wave_max_to_lane63(m);
    float wavemax =
        __int_as_float(__builtin_amdgcn_readlane(__float_as_int(wm), 63));
    unsigned long long bal = __ballot(m == wavemax);
    int firstlane = (int)__builtin_ctzll(bal);
    int widx = __builtin_amdgcn_readlane(p0 + li, firstlane);
    // packed key: high = f32 bits (monotone for +finite), low = 8191-idx.
    unsigned long long key =
        ((unsigned long long)__float_as_uint(wavemax) << 32) |
        (unsigned)(8191 - widx);
    if (lane == 0) s_red[r & 1][w] = key;
    __syncthreads();
    {  // parallel cross-wave reduce: 8 broadcast LDS reads + u64 max tree
      const unsigned long long* sr = s_red[r & 1];
      unsigned long long k0 = sr[0], k1 = sr[1], k2 = sr[2], k3 = sr[3];
      unsigned long long k4 = sr[4], k5 = sr[5], k6 = sr[6], k7 = sr[7];
      unsigned long long a = k0 > k1 ? k0 : k1;
      unsigned long long c = k2 > k3 ? k2 : k3;
      unsigned long long e = k4 > k5 ? k4 : k5;
      unsigned long long g = k6 > k7 ? k6 : k7;
      unsigned long long ac = a > c ? a : c;
      unsigned long long eg = e > g ? e : g;
      unsigned long long kmax = ac > eg ? ac : eg;
      const int bi = 8191 - (int)(unsigned)(kmax & 0xffffffffull);
      float4 cc = s_xyz4[bi];  // ONE ds_read_b128, broadcast
      lx = cc.x; ly = cc.y; lz = cc.z;
    }
    if (t == 0) {
      s_ctr[r * 3 + 0] = lx; s_ctr[r * 3 + 1] = ly; s_ctr[r * 3 + 2] = lz;
    }
    // Lagged publish (wave 0, every 16 rounds): release prog for chunk k-1,
    // then relaxed-store chunk k's 48 coords (16 rounds to drain).
    if (w == 0 && (r & 15) == 15) {
      int k16 = r >> 4;
      if (lane == 0 && k16 >= 1)
        __hip_atomic_store(&P.prog[b * 64], (unsigned)(k16 * 16),
                           __ATOMIC_RELEASE, __HIP_MEMORY_SCOPE_AGENT);
      int cbase = (r - 15) * 3;
      if (lane < 48)
        __hip_atomic_store(P.ctrs + (size_t)b * (S * 3) + cbase + lane,
                           s_ctr[cbase + lane], __ATOMIC_RELAXED,
                           __HIP_MEMORY_SCOPE_AGENT);
    }
  }
  __syncthreads();  // s_ctr complete before cooperative writeout
  if (w == 0 && lane == 0)  // final release covers the last chunk
    __hip_atomic_store(&P.prog[b * 64], (unsigned)S, __ATOMIC_RELEASE,
                       __HIP_MEMORY_SCOPE_AGENT);
  float* o = P.new_xyz + (size_t)b * S * 3;
  for (int i = t; i < (S * 3) / 4; i += THREADS)
    ((float4*)o)[i] = ((const float4*)s_ctr)[i];
}

// ---------------------------------------------------------------------------
// Consumer: one wave per center (8 waves/block). Spin (s_sleep backoff) until
// the producer publishes center (b,s); ball query fused with coord gather;
// 3-layer BN-folded MLP + max. No block barriers (same-wave LDS RAW only).
// ---------------------------------------------------------------------------
__device__ __forceinline__ void consumer(const KParams& P, char* smem, int cid,
                                         int t, int lane, int w) {
#pragma clang fp contract(off)
  constexpr float R2 = (float)(0.2 * 0.2);
  float* h = (float*)smem + w * (NS * 64);              // 8 KB per wave
  float* cs = (float*)smem + 8 * NS * 64 + w * (NS * 4);
  const unsigned gw = cid * 8 + w;  // global consumer wave id, 0..1983
  // BN-folded weights, loaded once per wave (registers)
  float sv1 = P.g1[lane] / sqrtf(P.v1[lane] + BN_EPS);
  float bb1 = (P.b1[lane] - P.m1[lane]) * sv1 + P.be1[lane];
  float w1x = P.w1[lane * 3 + 0] * sv1, w1y = P.w1[lane * 3 + 1] * sv1,
        w1z = P.w1[lane * 3 + 2] * sv1;
  float sv2 = P.g2[lane] / sqrtf(P.v2[lane] + BN_EPS);
  float bb2 = (P.b2[lane] - P.m2[lane]) * sv2 + P.be2[lane];
  float W2[64];
#pragma unroll
  for (int k = 0; k < 64; k += 4) {
    float4 q = *(const float4*)(P.w2 + lane * 64 + k);
    W2[k + 0] = q.x * sv2; W2[k + 1] = q.y * sv2;
    W2[k + 2] = q.z * sv2; W2[k + 3] = q.w * sv2;
  }
  float sva = P.g3[lane] / sqrtf(P.v3[lane] + BN_EPS);
  float bba = (P.b3[lane] - P.m3[lane]) * sva + P.be3[lane];
  float svb = P.g3[lane + 64] / sqrtf(P.v3[lane + 64] + BN_EPS);
  float bbb = (P.b3[lane + 64] - P.m3[lane + 64]) * svb + P.be3[lane + 64];
  float Wa[64], Wb[64];
#pragma unroll
  for (int k = 0; k < 64; k += 4) {
    float4 qa = *(const float4*)(P.w3 + lane * 64 + k);
    Wa[k + 0] = qa.x * sva; Wa[k + 1] = qa.y * sva;
    Wa[k + 2] = qa.z * sva; Wa[k + 3] = qa.w * sva;
    float4 qb = *(const float4*)(P.w3 + (lane + 64) * 64 + k);
    Wb[k + 0] = qb.x * svb; Wb[k + 1] = qb.y * svb;
    Wb[k + 2] = qb.z * svb; Wb[k + 3] = qb.w * svb;
  }
  for (unsigned c = gw; c < B * S; c += NCONS_WAVE) {
    const int b = c & 7;
    const int s = c >> 3;
    while (__hip_atomic_load(&P.prog[b * 64], __ATOMIC_RELAXED,
                             __HIP_MEMORY_SCOPE_AGENT) <= (unsigned)s)
      __builtin_amdgcn_s_sleep(8);
    (void)__hip_atomic_load(&P.prog[b * 64], __ATOMIC_ACQUIRE,
                            __HIP_MEMORY_SCOPE_AGENT);
    const float* cg = P.ctrs + (size_t)b * (S * 3) + s * 3;
    float cx = __hip_atomic_load(cg + 0, __ATOMIC_RELAXED,
                                 __HIP_MEMORY_SCOPE_AGENT);
    float cy = __hip_atomic_load(cg + 1, __ATOMIC_RELAXED,
                                 __HIP_MEMORY_SCOPE_AGENT);
    float cz = __hip_atomic_load(cg + 2, __ATOMIC_RELAXED,
                                 __HIP_MEMORY_SCOPE_AGENT);
    const float* base = P.xyz + (size_t)b * N * 3;
    // ball query fused with coord gather: finder lane scatters coords to cs
    int cnt = 0;
    for (int c0 = 0; c0 < N && cnt < NS; c0 += 64) {
      int p = c0 + lane;
      float x = base[p * 3], y = base[p * 3 + 1], z = base[p * 3 + 2];
      float dx = x - cx, dy = y - cy, dz = z - cz;
      float d = (dx * dx + dy * dy) + dz * dz;
      bool v = d < R2;  // strict <, exact fp32: matches reference
      unsigned long long mk = __ballot(v);
      int rank = cnt + __popcll(mk & ((1ull << lane) - 1ull));
      if (v && rank < NS) {
        cs[rank * 4 + 0] = x; cs[rank * 4 + 1] = y; cs[rank * 4 + 2] = z;
      }
      cnt += (int)__popcll(mk);
    }
    if (cnt < NS) {  // pad -> point 0 coords (pytorch3d clamp semantics)
      float x0 = base[0], y0 = base[1], z0 = base[2];
      for (int j = cnt + lane; j < NS; j += 64) {
        cs[j * 4 + 0] = x0; cs[j * 4 + 1] = y0; cs[j * 4 + 2] = z0;
      }
    }
    // layer 1: 3 -> 64
    for (int n = 0; n < NS; ++n) {
      float a = fmaf(w1x, cs[n * 4 + 0],
                     fmaf(w1y, cs[n * 4 + 1], fmaf(w1z, cs[n * 4 + 2], bb1)));
      h[n * 64 + lane] = fmaxf(a, 0.f);
    }
    // layer 2: 64 -> 64 (in-place row overwrite, wave-lockstep safe)
    for (int n = 0; n < NS; ++n) {
      float acc = bb2;
#pragma unroll
      for (int k = 0; k < 64; k += 4) {
        float4 q = *(const float4*)(h + n * 64 + k);
        acc = fmaf(W2[k + 0], q.x, acc);
        acc = fmaf(W2[k + 1], q.y, acc);
        acc = fmaf(W2[k + 2], q.z, acc);
        acc = fmaf(W2[k + 3], q.w, acc);
      }
      h[n * 64 + lane] = fmaxf(acc, 0.f);
    }
    // layer 3: 64 -> 128, both halves per pass, fused max over samples
    float mxa = 0.f, mxb = 0.f;
    for (int n = 0; n < NS; ++n) {
      float acca = bba, accb = bbb;
#pragma unroll
      for (int k = 0; k < 64; k += 4) {
        float4 q = *(const float4*)(h + n * 64 + k);
        acca = fmaf(Wa[k + 0], q.x, acca);
        acca = fmaf(Wa[k + 1], q.y, acca);
        acca = fmaf(Wa[k + 2], q.z, acca);
        acca = fmaf(Wa[k + 3], q.w, acca);
        accb = fmaf(Wb[k + 0], q.x, accb);
        accb = fmaf(Wb[k + 1], q.y, accb);
        accb = fmaf(Wb[k + 2], q.z, accb);
        accb = fmaf(Wb[k + 3], q.w, accb);
      }
      mxa = fmaxf(mxa, acca);
      mxb = fmaxf(mxb, accb);
    }
    P.out_feat[((size_t)b * 128 + lane) * S + s] = mxa;
    P.out_feat[((size_t)b * 128 + 64 + lane) * S + s] = mxb;
  }
}

// ---------------------------------------------------------------------------
__global__ void __attribute__((amdgpu_flat_work_group_size(THREADS, THREADS),
                               amdgpu_waves_per_eu(2, 2)))
k_fused(KParams P) {
  extern __shared__ char smem[];
  const int t = threadIdx.x;
  const int lane = t & 63;
  const int w = t >> 6;
  if (blockIdx.x < B)
    producer(P, smem, blockIdx.x, t, lane, w);
  else
    consumer(P, smem, blockIdx.x - B, t, lane, w);
}

// ---------------------------------------------------------------------------
extern "C" void kernel_launch(void* const* d_in, const int* in_sizes, int n_in,
                              void* d_out, int out_size, void* d_ws,
                              size_t ws_size, hipStream_t stream) {
  KParams P;
  P.xyz = (const float*)d_in[0];
  P.w1 = (const float*)d_in[1];  P.b1 = (const float*)d_in[2];
  P.g1 = (const float*)d_in[3];  P.be1 = (const float*)d_in[4];
  P.m1 = (const float*)d_in[5];  P.v1 = (const float*)d_in[6];
  P.w2 = (const float*)d_in[7];  P.b2 = (const float*)d_in[8];
  P.g2 = (const float*)d_in[9];  P.be2 = (const float*)d_in[10];
  P.m2 = (const float*)d_in[11]; P.v2 = (const float*)d_in[12];
  P.w3 = (const float*)d_in[13]; P.b3 = (const float*)d_in[14];
  P.g3 = (const float*)d_in[15]; P.be3 = (const float*)d_in[16];
  P.m3 = (const float*)d_in[17]; P.v3 = (const float*)d_in[18];
  float* out = (float*)d_out;
  P.new_xyz = out;
  P.out_feat = out + (size_t)B * S * 3;
  P.prog = (unsigned*)d_ws;                       // 8 x 64 u32 = 2 KB
  P.ctrs = (float*)((char*)d_ws + 2048);          // 96 KB

  // d_ws is re-poisoned to 0xAA before every timed launch: zero the progress
  // counters (async, graph-capturable) or consumers would see garbage.
  hipMemsetAsync(d_ws, 0, 2048, stream);

  // Plain launch (coop added ~55 us overhead, measured R9 vs R11). 256
  // blocks x 140 KB LDS -> 1 block/CU; correctness does not require
  // co-residency (late consumers find prog already advanced).
  dim3 grid(B + NCONS_BLK), blk(THREADS);
  size_t shmem = 131072 + 12288 + 256;  // producer overlay is the max
  k_fused<<<grid, blk, shmem, stream>>>(P);
}

// Round 13
// 912.963 us; speedup vs baseline: 1.0929x; 1.0790x over previous
//
#include <hip/hip_runtime.h>

#define B 8
#define N 8192
#define S 1024
#define NS 32
#define THREADS 256
#define NCONS_BLK 248
#define NCONS_WAVE (NCONS_BLK * 4)
constexpr float BN_EPS = 1e-5f;

typedef float v2f __attribute__((ext_vector_type(2)));

struct KParams {
  const float* xyz;
  const float *w1, *b1, *g1, *be1, *m1, *v1;
  const float *w2, *b2, *g2, *be2, *m2, *v2;
  const float *w3, *b3, *g3, *be3, *m3, *v3;
  float* new_xyz;   // d_out (B,S,3)
  float* out_feat;  // d_out + B*S*3 (B,128,S)
  float* ctrs;      // d_ws+2048: (B, S*3) published centers
  unsigned* prog;   // d_ws: per-batch progress counter, 64-int stride
};

// DPP-based full-wave (64-lane) f32 max; result valid in lane 63.
__device__ __forceinline__ float wave_max_to_lane63(float x) {
  int v = __float_as_int(x);
#define DPP_MAX(ctrl)                                                     \
  v = __float_as_int(fmaxf(__int_as_float(v),                             \
      __int_as_float(__builtin_amdgcn_update_dpp(v, v, (ctrl), 0xf, 0xf, \
                                                 false))))
  DPP_MAX(0x111);
  DPP_MAX(0x112);
  DPP_MAX(0x114);
  DPP_MAX(0x118);
  DPP_MAX(0x142);
  DPP_MAX(0x143);
#undef DPP_MAX
  return __int_as_float(v);
}

// ---------------------------------------------------------------------------
// Producer: FPS, 4 waves (1/SIMD), 32 pts/thread. EXACTLY the R9/R10
// structure that measured 832 us three times (invariant across register
// budgets -> latency-bound, leave it alone). One s_barrier per round
// (R11 proved spin-exchange is ~100 us worse), parallel 4-key LDS reduce,
// float4 LDS mirror for 1-instr winner-coord broadcast, lagged publish
// every 8 rounds.
// Exact contract-off fp32 distance math -> argmax matches NumPy bit-for-bit;
// ties -> smallest index (prefer-left walk-down + (8191-idx) key low word).
// ---------------------------------------------------------------------------
__device__ __forceinline__ void producer(const KParams& P, char* smem, int b,
                                         int t, int lane, int w) {
#pragma clang fp contract(off)
  float4* s_xyz4 = (float4*)smem;                       // 128 KB
  float* s_ctr = (float*)(smem + 131072);               // 12 KB
  unsigned long long(*s_red)[4] =
      (unsigned long long(*)[4])(smem + 131072 + 12288);
  const float* base = P.xyz + (size_t)b * N * 3;
  v2f X[16], Y[16], Z[16], D[16];
  const int p0 = t * 32;
  {
    // 32 pts * 3 floats = 24 float4 loads, 16B-aligned (t*384 bytes);
    // mirrored float4-strided into LDS for 1-instr winner-coord broadcast.
    const float4* src = (const float4*)(base + (size_t)p0 * 3);
    float buf[96];
#pragma unroll
    for (int i = 0; i < 24; ++i) {
      float4 v = src[i];
      buf[4 * i + 0] = v.x; buf[4 * i + 1] = v.y;
      buf[4 * i + 2] = v.z; buf[4 * i + 3] = v.w;
    }
#pragma unroll
    for (int k = 0; k < 32; ++k)
      s_xyz4[p0 + k] =
          make_float4(buf[3 * k], buf[3 * k + 1], buf[3 * k + 2], 0.f);
#pragma unroll
    for (int i = 0; i < 16; ++i) {
      X[i] = (v2f){buf[6 * i + 0], buf[6 * i + 3]};
      Y[i] = (v2f){buf[6 * i + 1], buf[6 * i + 4]};
      Z[i] = (v2f){buf[6 * i + 2], buf[6 * i + 5]};
      D[i] = (v2f){3.4e38f, 3.4e38f};  // ref init +inf; min(inf,d)=d, d<=3
    }
  }
  float lx = base[0], ly = base[1], lz = base[2];  // start index 0
  if (t == 0) { s_ctr[0] = lx; s_ctr[1] = ly; s_ctr[2] = lz; }
  for (int r = 1; r < S; ++r) {
    v2f lx2 = lx, ly2 = ly, lz2 = lz;
    // exact: d = ((dx*dx)+(dy*dy))+(dz*dz), contraction off; pk ops round
    // identically to scalar per lane-half.
#pragma unroll
    for (int i = 0; i < 16; ++i) {
      v2f dx = X[i] - lx2, dy = Y[i] - ly2, dz = Z[i] - lz2;
      v2f d = (dx * dx + dy * dy) + dz * dz;
      D[i] = __builtin_elementwise_min(D[i], d);
    }
    // local max tree over 32 halves; prefer-left walk-down == first index
    float n1[16], n2[8], n3[4], n4[2];
#pragma unroll
    for (int i = 0; i < 16; ++i) n1[i] = fmaxf(D[i].x, D[i].y);
#pragma unroll
    for (int i = 0; i < 8; ++i) n2[i] = fmaxf(n1[2 * i], n1[2 * i + 1]);
#pragma unroll
    for (int i = 0; i < 4; ++i) n3[i] = fmaxf(n2[2 * i], n2[2 * i + 1]);
    n4[0] = fmaxf(n3[0], n3[1]);
    n4[1] = fmaxf(n3[2], n3[3]);
    float m = fmaxf(n4[0], n4[1]);
    int c4 = (n4[0] < m) ? 1 : 0;
    float n3s = c4 ? n3[2] : n3[0];
    int c3 = (n3s < m) ? 1 : 0;
    float n2a = c4 ? n2[4] : n2[0];
    float n2b = c4 ? n2[6] : n2[2];
    float n2s = c3 ? n2b : n2a;
    int c2 = (n2s < m) ? 1 : 0;
    float n1a = c4 ? n1[8] : n1[0];
    float n1b = c4 ? n1[10] : n1[2];
    float n1c = c4 ? n1[12] : n1[4];
    float n1d = c4 ? n1[14] : n1[6];
    float n1e = c3 ? n1c : n1a;
    float n1f = c3 ? n1d : n1b;
    float n1s = c2 ? n1f : n1e;
    int c1 = (n1s < m) ? 1 : 0;
    float e0 = c4 ? D[8].x : D[0].x;
    float e1 = c4 ? D[9].x : D[1].x;
    float e2 = c4 ? D[10].x : D[2].x;
    float e3 = c4 ? D[11].x : D[3].x;
    float e4 = c4 ? D[12].x : D[4].x;
    float e5 = c4 ? D[13].x : D[5].x;
    float e6 = c4 ? D[14].x : D[6].x;
    float e7 = c4 ? D[15].x : D[7].x;
    float f0 = c3 ? e4 : e0;
    float f1 = c3 ? e5 : e1;
    float f2 = c3 ? e6 : e2;
    float f3 = c3 ? e7 : e3;
    float g0 = c2 ? f2 : f0;
    float g1 = c2 ? f3 : f1;
    float dxs = c1 ? g1 : g0;
    int c0 = (dxs < m) ? 1 : 0;
    int li = 16 * c4 + 8 * c3 + 4 * c2 + 2 * c1 + c0;
    // wave max via DPP; index recovery via ballot (lane order == index order)
    float wm = wave_max_to_lane63(m);
    float wavemax =
        __int_as_float(__builtin_amdgcn_readlane(__float_as_int(wm), 63));
    unsigned long long bal = __ballot(m == wavemax);
    int firstlane = (int)__builtin_ctzll(bal);
    int widx = __builtin_amdgcn_readlane(p0 + li, firstlane);
    unsigned long long key =
        ((unsigned long long)__float_as_uint(wavemax) << 32) |
        (unsigned)(8191 - widx);
    if (lane == 0) s_red[r & 1][w] = key;
    __syncthreads();
    {  // parallel cross-wave reduce: 4 broadcast LDS reads + u64 max tree
      const unsigned long long* sr = s_red[r & 1];
      unsigned long long k0 = sr[0], k1 = sr[1], k2 = sr[2], k3 = sr[3];
      unsigned long long a = k0 > k1 ? k0 : k1;
      unsigned long long c = k2 > k3 ? k2 : k3;
      unsigned long long kmax = a > c ? a : c;
      const int bi = 8191 - (int)(unsigned)(kmax & 0xffffffffull);
      float4 cc = s_xyz4[bi];  // ONE ds_read_b128, broadcast
      lx = cc.x; ly = cc.y; lz = cc.z;
    }
    if (t == 0) {
      s_ctr[r * 3 + 0] = lx; s_ctr[r * 3 + 1] = ly; s_ctr[r * 3 + 2] = lz;
    }
    // Lagged publish: release prog for chunk k-1 (its stores drained 8
    // rounds ago -> vmcnt(0) instant), then relaxed-store chunk k's coords.
    if (w == 0 && (r & 7) == 7) {
      int k8 = r >> 3;
      if (lane == 0 && k8 >= 1)
        __hip_atomic_store(&P.prog[b * 64], (unsigned)(k8 * 8),
                           __ATOMIC_RELEASE, __HIP_MEMORY_SCOPE_AGENT);
      int cbase = (r - 7) * 3;
      if (lane < 24)
        __hip_atomic_store(P.ctrs + (size_t)b * (S * 3) + cbase + lane,
                           s_ctr[cbase + lane], __ATOMIC_RELAXED,
                           __HIP_MEMORY_SCOPE_AGENT);
    }
  }
  __syncthreads();
  if (w == 0 && lane == 0)  // final release covers the last 2 chunks
    __hip_atomic_store(&P.prog[b * 64], (unsigned)S, __ATOMIC_RELEASE,
                       __HIP_MEMORY_SCOPE_AGENT);
  float* o = P.new_xyz + (size_t)b * S * 3;
  for (int i = t; i < (S * 3) / 4; i += THREADS)
    ((float4*)o)[i] = ((const float4*)s_ctr)[i];
}

// ---------------------------------------------------------------------------
// Consumer: one wave per center (4 waves/block). Spin (s_sleep backoff) until
// the producer publishes center (b,s); ball query fused with coord gather;
// 3-layer BN-folded MLP + max. No block barriers (same-wave LDS RAW only).
// ---------------------------------------------------------------------------
__device__ __forceinline__ void consumer(const KParams& P, char* smem, int cid,
                                         int t, int lane, int w) {
#pragma clang fp contract(off)
  constexpr float R2 = (float)(0.2 * 0.2);
  float* h = (float*)smem + w * (NS * 64);              // 8 KB per wave
  float* cs = (float*)smem + 4 * NS * 64 + w * (NS * 4);
  const unsigned gw = cid * 4 + w;  // global consumer wave id, 0..991
  // BN-folded weights, loaded once per wave (registers)
  float sv1 = P.g1[lane] / sqrtf(P.v1[lane] + BN_EPS);
  float bb1 = (P.b1[lane] - P.m1[lane]) * sv1 + P.be1[lane];
  float w1x = P.w1[lane * 3 + 0] * sv1, w1y = P.w1[lane * 3 + 1] * sv1,
        w1z = P.w1[lane * 3 + 2] * sv1;
  float sv2 = P.g2[lane] / sqrtf(P.v2[lane] + BN_EPS);
  float bb2 = (P.b2[lane] - P.m2[lane]) * sv2 + P.be2[lane];
  float W2[64];
#pragma unroll
  for (int k = 0; k < 64; k += 4) {
    float4 q = *(const float4*)(P.w2 + lane * 64 + k);
    W2[k + 0] = q.x * sv2; W2[k + 1] = q.y * sv2;
    W2[k + 2] = q.z * sv2; W2[k + 3] = q.w * sv2;
  }
  float sva = P.g3[lane] / sqrtf(P.v3[lane] + BN_EPS);
  float bba = (P.b3[lane] - P.m3[lane]) * sva + P.be3[lane];
  float svb = P.g3[lane + 64] / sqrtf(P.v3[lane + 64] + BN_EPS);
  float bbb = (P.b3[lane + 64] - P.m3[lane + 64]) * svb + P.be3[lane + 64];
  float Wa[64], Wb[64];
#pragma unroll
  for (int k = 0; k < 64; k += 4) {
    float4 qa = *(const float4*)(P.w3 + lane * 64 + k);
    Wa[k + 0] = qa.x * sva; Wa[k + 1] = qa.y * sva;
    Wa[k + 2] = qa.z * sva; Wa[k + 3] = qa.w * sva;
    float4 qb = *(const float4*)(P.w3 + (lane + 64) * 64 + k);
    Wb[k + 0] = qb.x * svb; Wb[k + 1] = qb.y * svb;
    Wb[k + 2] = qb.z * svb; Wb[k + 3] = qb.w * svb;
  }
  for (unsigned c = gw; c < B * S; c += NCONS_WAVE) {
    const int b = c & 7;
    const int s = c >> 3;
    while (__hip_atomic_load(&P.prog[b * 64], __ATOMIC_RELAXED,
                             __HIP_MEMORY_SCOPE_AGENT) <= (unsigned)s)
      __builtin_amdgcn_s_sleep(8);
    (void)__hip_atomic_load(&P.prog[b * 64], __ATOMIC_ACQUIRE,
                            __HIP_MEMORY_SCOPE_AGENT);
    const float* cg = P.ctrs + (size_t)b * (S * 3) + s * 3;
    float cx = __hip_atomic_load(cg + 0, __ATOMIC_RELAXED,
                                 __HIP_MEMORY_SCOPE_AGENT);
    float cy = __hip_atomic_load(cg + 1, __ATOMIC_RELAXED,
                                 __HIP_MEMORY_SCOPE_AGENT);
    float cz = __hip_atomic_load(cg + 2, __ATOMIC_RELAXED,
                                 __HIP_MEMORY_SCOPE_AGENT);
    const float* base = P.xyz + (size_t)b * N * 3;
    // ball query fused with coord gather: finder lane scatters coords to cs
    int cnt = 0;
    for (int c0 = 0; c0 < N && cnt < NS; c0 += 64) {
      int p = c0 + lane;
      float x = base[p * 3], y = base[p * 3 + 1], z = base[p * 3 + 2];
      float dx = x - cx, dy = y - cy, dz = z - cz;
      float d = (dx * dx + dy * dy) + dz * dz;
      bool v = d < R2;  // strict <, exact fp32: matches reference
      unsigned long long mk = __ballot(v);
      int rank = cnt + __popcll(mk & ((1ull << lane) - 1ull));
      if (v && rank < NS) {
        cs[rank * 4 + 0] = x; cs[rank * 4 + 1] = y; cs[rank * 4 + 2] = z;
      }
      cnt += (int)__popcll(mk);
    }
    if (cnt < NS) {  // pad -> point 0 coords (pytorch3d clamp semantics)
      float x0 = base[0], y0 = base[1], z0 = base[2];
      for (int j = cnt + lane; j < NS; j += 64) {
        cs[j * 4 + 0] = x0; cs[j * 4 + 1] = y0; cs[j * 4 + 2] = z0;
      }
    }
    // layer 1: 3 -> 64
    for (int n = 0; n < NS; ++n) {
      float a = fmaf(w1x, cs[n * 4 + 0],
                     fmaf(w1y, cs[n * 4 + 1], fmaf(w1z, cs[n * 4 + 2], bb1)));
      h[n * 64 + lane] = fmaxf(a, 0.f);
    }
    // layer 2: 64 -> 64 (in-place row overwrite, wave-lockstep safe)
    for (int n = 0; n < NS; ++n) {
      float acc = bb2;
#pragma unroll
      for (int k = 0; k < 64; k += 4) {
        float4 q = *(const float4*)(h + n * 64 + k);
        acc = fmaf(W2[k + 0], q.x, acc);
        acc = fmaf(W2[k + 1], q.y, acc);
        acc = fmaf(W2[k + 2], q.z, acc);
        acc = fmaf(W2[k + 3], q.w, acc);
      }
      h[n * 64 + lane] = fmaxf(acc, 0.f);
    }
    // layer 3: 64 -> 128, both halves per pass, fused max over samples
    float mxa = 0.f, mxb = 0.f;
    for (int n = 0; n < NS; ++n) {
      float acca = bba, accb = bbb;
#pragma unroll
      for (int k = 0; k < 64; k += 4) {
        float4 q = *(const float4*)(h + n * 64 + k);
        acca = fmaf(Wa[k + 0], q.x, acca);
        acca = fmaf(Wa[k + 1], q.y, acca);
        acca = fmaf(Wa[k + 2], q.z, acca);
        acca = fmaf(Wa[k + 3], q.w, acca);
        accb = fmaf(Wb[k + 0], q.x, accb);
        accb = fmaf(Wb[k + 1], q.y, accb);
        accb = fmaf(Wb[k + 2], q.z, accb);
        accb = fmaf(Wb[k + 3], q.w, accb);
      }
      mxa = fmaxf(mxa, acca);
      mxb = fmaxf(mxb, accb);
    }
    P.out_feat[((size_t)b * 128 + lane) * S + s] = mxa;
    P.out_feat[((size_t)b * 128 + 64 + lane) * S + s] = mxb;
  }
}

// ---------------------------------------------------------------------------
__global__ void __attribute__((amdgpu_flat_work_group_size(THREADS, THREADS),
                               amdgpu_waves_per_eu(1, 1)))
k_fused(KParams P) {
  extern __shared__ char smem[];
  const int t = threadIdx.x;
  const int lane = t & 63;
  const int w = t >> 6;
  if (blockIdx.x < B)
    producer(P, smem, blockIdx.x, t, lane, w);
  else
    consumer(P, smem, blockIdx.x - B, t, lane, w);
}

// ---------------------------------------------------------------------------
extern "C" void kernel_launch(void* const* d_in, const int* in_sizes, int n_in,
                              void* d_out, int out_size, void* d_ws,
                              size_t ws_size, hipStream_t stream) {
  KParams P;
  P.xyz = (const float*)d_in[0];
  P.w1 = (const float*)d_in[1];  P.b1 = (const float*)d_in[2];
  P.g1 = (const float*)d_in[3];  P.be1 = (const float*)d_in[4];
  P.m1 = (const float*)d_in[5];  P.v1 = (const float*)d_in[6];
  P.w2 = (const float*)d_in[7];  P.b2 = (const float*)d_in[8];
  P.g2 = (const float*)d_in[9];  P.be2 = (const float*)d_in[10];
  P.m2 = (const float*)d_in[11]; P.v2 = (const float*)d_in[12];
  P.w3 = (const float*)d_in[13]; P.b3 = (const float*)d_in[14];
  P.g3 = (const float*)d_in[15]; P.be3 = (const float*)d_in[16];
  P.m3 = (const float*)d_in[17]; P.v3 = (const float*)d_in[18];
  float* out = (float*)d_out;
  P.new_xyz = out;
  P.out_feat = out + (size_t)B * S * 3;
  P.prog = (unsigned*)d_ws;                       // 8 x 64 u32 = 2 KB
  P.ctrs = (float*)((char*)d_ws + 2048);          // 96 KB

  // d_ws is re-poisoned to 0xAA before every timed launch: zero the progress
  // counters (async, graph-capturable) or consumers would see garbage.
  hipMemsetAsync(d_ws, 0, 2048, stream);

  // Plain launch (coop costs ~55 us, measured R10-vs-R11 gap). 256 blocks x
  // 140 KB LDS -> 1 block/CU; correctness does not require co-residency
  // (late consumer blocks find prog already advanced and just process).
  dim3 grid(B + NCONS_BLK), blk(THREADS);
  size_t shmem = 131072 + 12288 + 256;  // producer overlay is the max
  k_fused<<<grid, blk, shmem, stream>>>(P);
}